// Round 10
// baseline (120.875 us; speedup 1.0000x reference)
//
#include <hip/hip_runtime.h>
#include <hip/hip_bf16.h>
#include <hip/hip_fp16.h>

typedef _Float16 half8_t  __attribute__((ext_vector_type(8)));
typedef short    short8_t __attribute__((ext_vector_type(8)));
typedef float    f32x4    __attribute__((ext_vector_type(4)));

#define LOG2E 1.44269504088896f

// ---------------------------------------------------------------------------
// Kernel 1 (v7): f = x@Wf+bf (f16, KEY-PERMUTED storage), g = (x@Wg+bg)*log2e
// (f16), v = x@Wh+bh (bf16, A-frag tiling).
//
// Key permutation (per 32-key block): slot s<16 holds physical key
// (s>>2)*8+(s&3); slot s>=16 holds (s>>2 of s-16)*8+((s-16)&3)+4. With this,
// the score MFMA's C-layout rows land so that lane(quad,l15) holds exp(S)
// for keys quad*8+{0..7} at q=l15 — which IS the PV B-operand layout.
// Inverse (store side): key r=q8*8+j -> slot = (j<4) ? q8*4+j : 16+q8*4+j-4.
//
// vT4[b][kblock][ch][r]: per 32-key block, 64ch x 32 keys contiguous (4KB);
// attn A-frag (ch=ct*16+l15, keys quad*8+j) = 16B contiguous.
// ---------------------------------------------------------------------------
__global__ __launch_bounds__(256) void prep_kernel(
    const float* __restrict__ x,
    const float* __restrict__ Wf, const float* __restrict__ bf,
    const float* __restrict__ Wg, const float* __restrict__ bg,
    const float* __restrict__ Wh, const float* __restrict__ bh,
    _Float16* __restrict__ fh, _Float16* __restrict__ gh,
    unsigned short* __restrict__ vT)
{
  __shared__ float XsT[64 * 33];
  __shared__ float Wall[64 * 80];
  __shared__ float ball[80];
  const int t  = threadIdx.x;
  const int p0 = blockIdx.x * 32;

  for (int i = t; i < 512; i += 256) {
    Wall[(i >> 3) * 80 + (i & 7)]     = Wf[i];
    Wall[(i >> 3) * 80 + 8 + (i & 7)] = Wg[i] * LOG2E;
  }
  for (int i = t; i < 4096; i += 256)
    Wall[(i >> 6) * 80 + 16 + (i & 63)] = Wh[i];
  if (t < 80) ball[t] = (t < 8) ? bf[t] : (t < 16) ? bg[t - 8] * LOG2E : bh[t - 16];

  const float4* xs = (const float4*)(x + (size_t)p0 * 64);
#pragma unroll
  for (int i = 0; i < 2; i++) {
    int idx = t + i * 256;
    int row = idx >> 4, c4 = idx & 15;
    float4 v = xs[idx];
    XsT[(c4 * 4 + 0) * 33 + row] = v.x;
    XsT[(c4 * 4 + 1) * 33 + row] = v.y;
    XsT[(c4 * 4 + 2) * 33 + row] = v.z;
    XsT[(c4 * 4 + 3) * 33 + row] = v.w;
  }
  __syncthreads();

  const int pos = t & 31;
  const int g   = t >> 5;
  const int cb  = g * 10;

  float acc[10];
#pragma unroll
  for (int j = 0; j < 10; j++) acc[j] = ball[cb + j];

  for (int c = 0; c < 64; c++) {
    float xv = XsT[c * 33 + pos];
    const float2* wr = (const float2*)&Wall[c * 80 + cb];
#pragma unroll
    for (int k = 0; k < 5; k++) {
      float2 w2 = wr[k];
      acc[2 * k]     += xv * w2.x;
      acc[2 * k + 1] += xv * w2.y;
    }
  }

  const size_t pg = (size_t)p0 + pos;
  const int b = (int)(pg >> 12);
  const int n = (int)(pg & 4095);
  const int kblock = n >> 5;
  const int r  = n & 31;          // physical key within 32-block
  const int q8 = r >> 3, j8 = r & 7;
  const int slot = (j8 < 4) ? (q8 * 4 + j8) : (16 + q8 * 4 + (j8 - 4));
  const size_t fpos = ((size_t)b * 4096 + (kblock << 5) + slot) * 8;   // f16 elems
  const size_t vbase = (((size_t)b * 128 + kblock) << 11) + r;         // shorts; +ch*32
#pragma unroll
  for (int jj = 0; jj < 10; jj++) {
    int ch = cb + jj;
    if (ch < 8) {
      fh[fpos + ch] = (_Float16)acc[jj];
    } else if (ch < 16) {
      gh[pg * 8 + (ch - 8)] = (_Float16)acc[jj];
    } else {
      __hip_bfloat16 hv = __float2bfloat16(acc[jj]);
      vT[vbase + (size_t)(ch - 16) * 32] = *(unsigned short*)&hv;
    }
  }
}

// ---------------------------------------------------------------------------
// Kernel 2 (v10): SHUFFLE-FREE flash attention (no-max softmax, base-2).
// 1024 blocks x 512 thr (8 waves); block = (batch, 16-q tile); wave w covers
// keys [w*512, +512). Scores via K32 f16 MFMA on key-permuted f (see prep):
// exp results are directly the PV B-frags. PV computed as out^T = V^T * P
// (V^T A-frags = contiguous 16B loads). Denominator via ones-A MFMA ->
// every lane holds l[q=l15]. Zero cross-lane ops in the whole main loop.
// ---------------------------------------------------------------------------
__device__ __forceinline__ unsigned pack_bf16_2(float lo, float hi) {
  float2 f2; f2.x = lo; f2.y = hi;
  __hip_bfloat162 h2 = __float22bfloat162_rn(f2);
  return *reinterpret_cast<unsigned*>(&h2);
}

__global__ __launch_bounds__(512, 6) void attn_kernel(
    const _Float16* __restrict__ fh,        // [B][N][8] f16, key-permuted slots
    const _Float16* __restrict__ gh,        // [B][N][8] f16 (x log2e)
    const unsigned short* __restrict__ vT,  // [b][kblock][ch][r] bf16
    float* __restrict__ out)                // [B][N][64] f32
{
  const int N    = 4096;
  const int lane = threadIdx.x & 63;
  const int w    = threadIdx.x >> 6;       // 0..7
  const int quad = lane >> 4;
  const int l15  = lane & 15;

  __shared__ float red[7][64][17];  // waves 1-7: 16 acc + 1 l per lane

  const int xcd = blockIdx.x & 7;
  const int b   = xcd >> 1;
  const int sub = ((blockIdx.x >> 3) << 1) + (xcd & 1);  // 0..255 q tile
  const int q0  = sub * 16;
  const int kbase = w * 512;

  const _Float16* fbase = fh + (size_t)b * N * 8;
  const _Float16* gbase = gh + (size_t)b * N * 8;
  // lane-fixed part of vT4 address (shorts): ch_low(l15)*32 + quad*8
  const short* vbat = (const short*)vT + (size_t)b * 262144 + (l15 << 5) + (quad << 3);

  // G B-frag: B[k=quad*8+j][n=q=l15]; only quad 0 carries real k (DK=8)
  half8_t gfrag = {};
  if (quad == 0) gfrag = *(const half8_t*)(gbase + (size_t)(q0 + l15) * 8);

  const f32x4 zc = {0.f, 0.f, 0.f, 0.f};
  f32x4 acc[4] = {zc, zc, zc, zc};   // D[ch=ct*16+quad*4+reg][q=l15] (out^T)
  f32x4 acc4   = zc;                 // every reg = l[q=l15] partial

  short8_t ones8;
#pragma unroll
  for (int i = 0; i < 8; i++) ones8[i] = (short)0x3F80;  // bf16 1.0

  half8_t f0 = {}, f1 = {};          // zero-init ONCE; non-quad0 lanes stay 0

#pragma unroll 8
  for (int cc = 0; cc < 16; cc++) {
    const int k0 = kbase + cc * 32;

    // f slot loads (quad 0 only): tile0 = slots 0-15, tile1 = slots 16-31
    if (quad == 0) {
      f0 = *(const half8_t*)(fbase + (size_t)(k0 + l15) * 8);
      f1 = *(const half8_t*)(fbase + (size_t)(k0 + 16 + l15) * 8);
    }
    // V^T A-frags: 4 x 1KB contiguous wave-loads from one 4KB block
    const short* vk = vbat + ((size_t)(k0 >> 5) << 11);
    short8_t v0 = *(const short8_t*)(vk);
    short8_t v1 = *(const short8_t*)(vk + 512);
    short8_t v2 = *(const short8_t*)(vk + 1024);
    short8_t v3 = *(const short8_t*)(vk + 1536);

    f32x4 s0 = __builtin_amdgcn_mfma_f32_16x16x32_f16(f0, gfrag, zc, 0, 0, 0);
    f32x4 s1 = __builtin_amdgcn_mfma_f32_16x16x32_f16(f1, gfrag, zc, 0, 0, 0);
    // key permutation => lane holds S^T for keys k0 + quad*8 + reg (s0)
    //                                 and keys k0 + quad*8 + 4 + reg (s1), q=l15

    float p00 = __builtin_amdgcn_exp2f(s0[0]), p01 = __builtin_amdgcn_exp2f(s0[1]);
    float p02 = __builtin_amdgcn_exp2f(s0[2]), p03 = __builtin_amdgcn_exp2f(s0[3]);
    float p10 = __builtin_amdgcn_exp2f(s1[0]), p11 = __builtin_amdgcn_exp2f(s1[1]);
    float p12 = __builtin_amdgcn_exp2f(s1[2]), p13 = __builtin_amdgcn_exp2f(s1[3]);

    // pack: pfrag[j] = P[key=quad*8+j][q=l15] — DIRECT B-operand, no shuffles
    union { unsigned u[4]; short8_t v; } pu;
    pu.u[0] = pack_bf16_2(p00, p01);
    pu.u[1] = pack_bf16_2(p02, p03);
    pu.u[2] = pack_bf16_2(p10, p11);
    pu.u[3] = pack_bf16_2(p12, p13);
    short8_t pfrag = pu.v;

    acc[0] = __builtin_amdgcn_mfma_f32_16x16x32_bf16(v0, pfrag, acc[0], 0, 0, 0);
    acc[1] = __builtin_amdgcn_mfma_f32_16x16x32_bf16(v1, pfrag, acc[1], 0, 0, 0);
    acc[2] = __builtin_amdgcn_mfma_f32_16x16x32_bf16(v2, pfrag, acc[2], 0, 0, 0);
    acc[3] = __builtin_amdgcn_mfma_f32_16x16x32_bf16(v3, pfrag, acc[3], 0, 0, 0);
    acc4   = __builtin_amdgcn_mfma_f32_16x16x32_bf16(ones8, pfrag, acc4, 0, 0, 0);
  }

  float lv = acc4[0];   // l[q=l15] partial for this wave's keys (all lanes)

  // cross-wave combine
  if (w > 0) {
    float* p = &red[w - 1][lane][0];
#pragma unroll
    for (int ct = 0; ct < 4; ct++)
#pragma unroll
      for (int reg = 0; reg < 4; reg++) p[ct * 4 + reg] = acc[ct][reg];
    p[16] = lv;
  }
  __syncthreads();
  if (w == 0) {
#pragma unroll
    for (int ww = 0; ww < 7; ww++) {
      const float* p = &red[ww][lane][0];
#pragma unroll
      for (int ct = 0; ct < 4; ct++)
#pragma unroll
        for (int reg = 0; reg < 4; reg++) acc[ct][reg] += p[ct * 4 + reg];
      lv += p[16];
    }
    const float inv = 1.0f / lv;   // this lane's q = l15, no shuffle needed
    // acc[ct][reg] = out[q=l15][ch=ct*16+quad*4+reg] -> contiguous f32x4 stores
    float* ob = out + ((size_t)b * N + q0 + l15) * 64 + (quad << 2);
#pragma unroll
    for (int ct = 0; ct < 4; ct++) {
      f32x4 rr = acc[ct] * inv;
      *(f32x4*)(ob + ct * 16) = rr;
    }
  }
}

// ---------------------------------------------------------------------------
extern "C" void kernel_launch(void* const* d_in, const int* in_sizes, int n_in,
                              void* d_out, int out_size, void* d_ws, size_t ws_size,
                              hipStream_t stream) {
  const float* x  = (const float*)d_in[0];
  const float* Wf = (const float*)d_in[1];
  const float* bf = (const float*)d_in[2];
  const float* Wg = (const float*)d_in[3];
  const float* bg = (const float*)d_in[4];
  const float* Wh = (const float*)d_in[5];
  const float* bh = (const float*)d_in[6];
  float* out = (float*)d_out;

  char* ws = (char*)d_ws;
  _Float16* fh = (_Float16*)ws;                        // 256 KB
  _Float16* gh = (_Float16*)(ws + 262144);             // 256 KB
  unsigned short* vT = (unsigned short*)(ws + 524288); // 2 MB

  prep_kernel<<<512, 256, 0, stream>>>(x, Wf, bf, Wg, bg, Wh, bh, fh, gh, vT);
  attn_kernel<<<1024, 512, 0, stream>>>(fh, gh, vT, out);
}

// Round 11
// 114.615 us; speedup vs baseline: 1.0546x; 1.0546x over previous
//
#include <hip/hip_runtime.h>
#include <hip/hip_bf16.h>
#include <hip/hip_fp16.h>

typedef _Float16 half8_t  __attribute__((ext_vector_type(8)));
typedef short    short8_t __attribute__((ext_vector_type(8)));
typedef float    f32x4    __attribute__((ext_vector_type(4)));

#define LOG2E 1.44269504088896f

// ---------------------------------------------------------------------------
// Kernel 1 (v7): f = x@Wf+bf (f16, KEY-PERMUTED storage), g = (x@Wg+bg)*log2e
// (f16), v = x@Wh+bh (bf16, A-frag tiling).
//
// Key permutation (per 32-key block): the score MFMA's C-layout rows land so
// that lane(quad,l15) holds exp(S) for keys quad*8+{0..7} at q=l15 — which IS
// the PV B-operand layout. Store side: key r=q8*8+j ->
// slot = (j<4) ? q8*4+j : 16+q8*4+(j-4).
//
// vT4[b][kblock][ch][r]: per 32-key block, 64ch x 32 keys contiguous (4KB);
// attn A-frag (ch=ct*16+l15, keys quad*8+j) = 16B contiguous.
// ---------------------------------------------------------------------------
__global__ __launch_bounds__(256) void prep_kernel(
    const float* __restrict__ x,
    const float* __restrict__ Wf, const float* __restrict__ bf,
    const float* __restrict__ Wg, const float* __restrict__ bg,
    const float* __restrict__ Wh, const float* __restrict__ bh,
    _Float16* __restrict__ fh, _Float16* __restrict__ gh,
    unsigned short* __restrict__ vT)
{
  __shared__ float XsT[64 * 33];
  __shared__ float Wall[64 * 80];
  __shared__ float ball[80];
  const int t  = threadIdx.x;
  const int p0 = blockIdx.x * 32;

  for (int i = t; i < 512; i += 256) {
    Wall[(i >> 3) * 80 + (i & 7)]     = Wf[i];
    Wall[(i >> 3) * 80 + 8 + (i & 7)] = Wg[i] * LOG2E;
  }
  for (int i = t; i < 4096; i += 256)
    Wall[(i >> 6) * 80 + 16 + (i & 63)] = Wh[i];
  if (t < 80) ball[t] = (t < 8) ? bf[t] : (t < 16) ? bg[t - 8] * LOG2E : bh[t - 16];

  const float4* xs = (const float4*)(x + (size_t)p0 * 64);
#pragma unroll
  for (int i = 0; i < 2; i++) {
    int idx = t + i * 256;
    int row = idx >> 4, c4 = idx & 15;
    float4 v = xs[idx];
    XsT[(c4 * 4 + 0) * 33 + row] = v.x;
    XsT[(c4 * 4 + 1) * 33 + row] = v.y;
    XsT[(c4 * 4 + 2) * 33 + row] = v.z;
    XsT[(c4 * 4 + 3) * 33 + row] = v.w;
  }
  __syncthreads();

  const int pos = t & 31;
  const int g   = t >> 5;
  const int cb  = g * 10;

  float acc[10];
#pragma unroll
  for (int j = 0; j < 10; j++) acc[j] = ball[cb + j];

  for (int c = 0; c < 64; c++) {
    float xv = XsT[c * 33 + pos];
    const float2* wr = (const float2*)&Wall[c * 80 + cb];
#pragma unroll
    for (int k = 0; k < 5; k++) {
      float2 w2 = wr[k];
      acc[2 * k]     += xv * w2.x;
      acc[2 * k + 1] += xv * w2.y;
    }
  }

  const size_t pg = (size_t)p0 + pos;
  const int b = (int)(pg >> 12);
  const int n = (int)(pg & 4095);
  const int kblock = n >> 5;
  const int r  = n & 31;          // physical key within 32-block
  const int q8 = r >> 3, j8 = r & 7;
  const int slot = (j8 < 4) ? (q8 * 4 + j8) : (16 + q8 * 4 + (j8 - 4));
  const size_t fpos = ((size_t)b * 4096 + (kblock << 5) + slot) * 8;   // f16 elems
  const size_t vbase = (((size_t)b * 128 + kblock) << 11) + r;         // shorts; +ch*32
#pragma unroll
  for (int jj = 0; jj < 10; jj++) {
    int ch = cb + jj;
    if (ch < 8) {
      fh[fpos + ch] = (_Float16)acc[jj];
    } else if (ch < 16) {
      gh[pg * 8 + (ch - 8)] = (_Float16)acc[jj];
    } else {
      __hip_bfloat16 hv = __float2bfloat16(acc[jj]);
      vT[vbase + (size_t)(ch - 16) * 32] = *(unsigned short*)&hv;
    }
  }
}

// ---------------------------------------------------------------------------
// Kernel 2 (v11): R10's shuffle-free flash attention, compiled WITHOUT the
// register squeeze. __launch_bounds__(512,4): every (512,6) build (R6/R7/R10,
// VGPR=40) emitted scratch traffic (WRITE 10-14MB) and ran 47-61 us; every
// (512,4) build (VGPR=64) ran ~36 us clean. Algorithm unchanged from R10:
// key-permuted scores -> exp results ARE the PV B-frags (zero cross-lane
// ops), V^T A-frags 16B contiguous, ones-A MFMA denominator, shuffle-free
// epilogue with contiguous f32x4 stores.
// ---------------------------------------------------------------------------
__device__ __forceinline__ unsigned pack_bf16_2(float lo, float hi) {
  float2 f2; f2.x = lo; f2.y = hi;
  __hip_bfloat162 h2 = __float22bfloat162_rn(f2);
  return *reinterpret_cast<unsigned*>(&h2);
}

__global__ __launch_bounds__(512, 4) void attn_kernel(
    const _Float16* __restrict__ fh,        // [B][N][8] f16, key-permuted slots
    const _Float16* __restrict__ gh,        // [B][N][8] f16 (x log2e)
    const unsigned short* __restrict__ vT,  // [b][kblock][ch][r] bf16
    float* __restrict__ out)                // [B][N][64] f32
{
  const int N    = 4096;
  const int lane = threadIdx.x & 63;
  const int w    = threadIdx.x >> 6;       // 0..7
  const int quad = lane >> 4;
  const int l15  = lane & 15;

  __shared__ float red[7][64][17];  // waves 1-7: 16 acc + 1 l per lane

  const int xcd = blockIdx.x & 7;
  const int b   = xcd >> 1;
  const int sub = ((blockIdx.x >> 3) << 1) + (xcd & 1);  // 0..255 q tile
  const int q0  = sub * 16;
  const int kbase = w * 512;

  const _Float16* fbase = fh + (size_t)b * N * 8;
  const _Float16* gbase = gh + (size_t)b * N * 8;
  // lane-fixed part of vT4 address (shorts): ch_low(l15)*32 + quad*8
  const short* vbat = (const short*)vT + (size_t)b * 262144 + (l15 << 5) + (quad << 3);

  // G B-frag: B[k=quad*8+j][n=q=l15]; only quad 0 carries real k (DK=8)
  half8_t gfrag = {};
  if (quad == 0) gfrag = *(const half8_t*)(gbase + (size_t)(q0 + l15) * 8);

  const f32x4 zc = {0.f, 0.f, 0.f, 0.f};
  f32x4 acc[4] = {zc, zc, zc, zc};   // D[ch=ct*16+quad*4+reg][q=l15] (out^T)
  f32x4 acc4   = zc;                 // every reg = l[q=l15] partial

  short8_t ones8;
#pragma unroll
  for (int i = 0; i < 8; i++) ones8[i] = (short)0x3F80;  // bf16 1.0

  half8_t f0 = {}, f1 = {};          // zero-init ONCE; non-quad0 lanes stay 0

#pragma unroll 8
  for (int cc = 0; cc < 16; cc++) {
    const int k0 = kbase + cc * 32;

    // f slot loads (quad 0 only): tile0 = slots 0-15, tile1 = slots 16-31
    if (quad == 0) {
      f0 = *(const half8_t*)(fbase + (size_t)(k0 + l15) * 8);
      f1 = *(const half8_t*)(fbase + (size_t)(k0 + 16 + l15) * 8);
    }
    // V^T A-frags: 4 x 1KB fully-contiguous wave-loads from one 4KB block
    const short* vk = vbat + ((size_t)(k0 >> 5) << 11);
    short8_t v0 = *(const short8_t*)(vk);
    short8_t v1 = *(const short8_t*)(vk + 512);
    short8_t v2 = *(const short8_t*)(vk + 1024);
    short8_t v3 = *(const short8_t*)(vk + 1536);

    f32x4 s0 = __builtin_amdgcn_mfma_f32_16x16x32_f16(f0, gfrag, zc, 0, 0, 0);
    f32x4 s1 = __builtin_amdgcn_mfma_f32_16x16x32_f16(f1, gfrag, zc, 0, 0, 0);
    // key permutation => lane holds S^T for keys k0 + quad*8 + reg (s0)
    //                                 and keys k0 + quad*8 + 4 + reg (s1), q=l15

    float p00 = __builtin_amdgcn_exp2f(s0[0]), p01 = __builtin_amdgcn_exp2f(s0[1]);
    float p02 = __builtin_amdgcn_exp2f(s0[2]), p03 = __builtin_amdgcn_exp2f(s0[3]);
    float p10 = __builtin_amdgcn_exp2f(s1[0]), p11 = __builtin_amdgcn_exp2f(s1[1]);
    float p12 = __builtin_amdgcn_exp2f(s1[2]), p13 = __builtin_amdgcn_exp2f(s1[3]);

    // pack: pfrag[j] = P[key=quad*8+j][q=l15] — DIRECT B-operand, no shuffles
    union { unsigned u[4]; short8_t v; } pu;
    pu.u[0] = pack_bf16_2(p00, p01);
    pu.u[1] = pack_bf16_2(p02, p03);
    pu.u[2] = pack_bf16_2(p10, p11);
    pu.u[3] = pack_bf16_2(p12, p13);
    short8_t pfrag = pu.v;

    acc[0] = __builtin_amdgcn_mfma_f32_16x16x32_bf16(v0, pfrag, acc[0], 0, 0, 0);
    acc[1] = __builtin_amdgcn_mfma_f32_16x16x32_bf16(v1, pfrag, acc[1], 0, 0, 0);
    acc[2] = __builtin_amdgcn_mfma_f32_16x16x32_bf16(v2, pfrag, acc[2], 0, 0, 0);
    acc[3] = __builtin_amdgcn_mfma_f32_16x16x32_bf16(v3, pfrag, acc[3], 0, 0, 0);
    acc4   = __builtin_amdgcn_mfma_f32_16x16x32_bf16(ones8, pfrag, acc4, 0, 0, 0);
  }

  float lv = acc4[0];   // l[q=l15] partial for this wave's keys (all lanes)

  // cross-wave combine
  if (w > 0) {
    float* p = &red[w - 1][lane][0];
#pragma unroll
    for (int ct = 0; ct < 4; ct++)
#pragma unroll
      for (int reg = 0; reg < 4; reg++) p[ct * 4 + reg] = acc[ct][reg];
    p[16] = lv;
  }
  __syncthreads();
  if (w == 0) {
#pragma unroll
    for (int ww = 0; ww < 7; ww++) {
      const float* p = &red[ww][lane][0];
#pragma unroll
      for (int ct = 0; ct < 4; ct++)
#pragma unroll
        for (int reg = 0; reg < 4; reg++) acc[ct][reg] += p[ct * 4 + reg];
      lv += p[16];
    }
    const float inv = 1.0f / lv;   // this lane's q = l15, no shuffle needed
    // acc[ct][reg] = out[q=l15][ch=ct*16+quad*4+reg] -> contiguous f32x4 stores
    float* ob = out + ((size_t)b * N + q0 + l15) * 64 + (quad << 2);
#pragma unroll
    for (int ct = 0; ct < 4; ct++) {
      f32x4 rr = acc[ct] * inv;
      *(f32x4*)(ob + ct * 16) = rr;
    }
  }
}

// ---------------------------------------------------------------------------
extern "C" void kernel_launch(void* const* d_in, const int* in_sizes, int n_in,
                              void* d_out, int out_size, void* d_ws, size_t ws_size,
                              hipStream_t stream) {
  const float* x  = (const float*)d_in[0];
  const float* Wf = (const float*)d_in[1];
  const float* bf = (const float*)d_in[2];
  const float* Wg = (const float*)d_in[3];
  const float* bg = (const float*)d_in[4];
  const float* Wh = (const float*)d_in[5];
  const float* bh = (const float*)d_in[6];
  float* out = (float*)d_out;

  char* ws = (char*)d_ws;
  _Float16* fh = (_Float16*)ws;                        // 256 KB
  _Float16* gh = (_Float16*)(ws + 262144);             // 256 KB
  unsigned short* vT = (unsigned short*)(ws + 524288); // 2 MB

  prep_kernel<<<512, 256, 0, stream>>>(x, Wf, bf, Wg, bg, Wh, bh, fh, gh, vT);
  attn_kernel<<<1024, 512, 0, stream>>>(fh, gh, vT, out);
}

// Round 12
// 107.246 us; speedup vs baseline: 1.1271x; 1.0687x over previous
//
#include <hip/hip_runtime.h>
#include <hip/hip_bf16.h>
#include <hip/hip_fp16.h>

typedef _Float16 half8_t  __attribute__((ext_vector_type(8)));
typedef short    short8_t __attribute__((ext_vector_type(8)));
typedef float    f32x4    __attribute__((ext_vector_type(4)));

#define LOG2E 1.44269504088896f

// ---------------------------------------------------------------------------
// Kernel 1 (v7, unchanged from R11): f = x@Wf+bf (f16, KEY-PERMUTED slots),
// g = (x@Wg+bg)*log2e (f16), v = x@Wh+bh (bf16, vT4 A-frag tiling).
// Key permutation: key r=q8*8+j -> slot = (j<4) ? q8*4+j : 16+q8*4+(j-4),
// so score-MFMA C-layout == PV B-operand layout (shuffle-free attn).
// vT4[b][kblock][ch][r]: 64ch x 32 keys contiguous 4KB per key-block.
// ---------------------------------------------------------------------------
__global__ __launch_bounds__(256) void prep_kernel(
    const float* __restrict__ x,
    const float* __restrict__ Wf, const float* __restrict__ bf,
    const float* __restrict__ Wg, const float* __restrict__ bg,
    const float* __restrict__ Wh, const float* __restrict__ bh,
    _Float16* __restrict__ fh, _Float16* __restrict__ gh,
    unsigned short* __restrict__ vT)
{
  __shared__ float XsT[64 * 33];
  __shared__ float Wall[64 * 80];
  __shared__ float ball[80];
  const int t  = threadIdx.x;
  const int p0 = blockIdx.x * 32;

  for (int i = t; i < 512; i += 256) {
    Wall[(i >> 3) * 80 + (i & 7)]     = Wf[i];
    Wall[(i >> 3) * 80 + 8 + (i & 7)] = Wg[i] * LOG2E;
  }
  for (int i = t; i < 4096; i += 256)
    Wall[(i >> 6) * 80 + 16 + (i & 63)] = Wh[i];
  if (t < 80) ball[t] = (t < 8) ? bf[t] : (t < 16) ? bg[t - 8] * LOG2E : bh[t - 16];

  const float4* xs = (const float4*)(x + (size_t)p0 * 64);
#pragma unroll
  for (int i = 0; i < 2; i++) {
    int idx = t + i * 256;
    int row = idx >> 4, c4 = idx & 15;
    float4 v = xs[idx];
    XsT[(c4 * 4 + 0) * 33 + row] = v.x;
    XsT[(c4 * 4 + 1) * 33 + row] = v.y;
    XsT[(c4 * 4 + 2) * 33 + row] = v.z;
    XsT[(c4 * 4 + 3) * 33 + row] = v.w;
  }
  __syncthreads();

  const int pos = t & 31;
  const int g   = t >> 5;
  const int cb  = g * 10;

  float acc[10];
#pragma unroll
  for (int j = 0; j < 10; j++) acc[j] = ball[cb + j];

  for (int c = 0; c < 64; c++) {
    float xv = XsT[c * 33 + pos];
    const float2* wr = (const float2*)&Wall[c * 80 + cb];
#pragma unroll
    for (int k = 0; k < 5; k++) {
      float2 w2 = wr[k];
      acc[2 * k]     += xv * w2.x;
      acc[2 * k + 1] += xv * w2.y;
    }
  }

  const size_t pg = (size_t)p0 + pos;
  const int b = (int)(pg >> 12);
  const int n = (int)(pg & 4095);
  const int kblock = n >> 5;
  const int r  = n & 31;
  const int q8 = r >> 3, j8 = r & 7;
  const int slot = (j8 < 4) ? (q8 * 4 + j8) : (16 + q8 * 4 + (j8 - 4));
  const size_t fpos = ((size_t)b * 4096 + (kblock << 5) + slot) * 8;
  const size_t vbase = (((size_t)b * 128 + kblock) << 11) + r;
#pragma unroll
  for (int jj = 0; jj < 10; jj++) {
    int ch = cb + jj;
    if (ch < 8) {
      fh[fpos + ch] = (_Float16)acc[jj];
    } else if (ch < 16) {
      gh[pg * 8 + (ch - 8)] = (_Float16)acc[jj];
    } else {
      __hip_bfloat16 hv = __float2bfloat16(acc[jj]);
      vT[vbase + (size_t)(ch - 16) * 32] = *(unsigned short*)&hv;
    }
  }
}

// ---------------------------------------------------------------------------
// Kernel 2 (v12): 64-QUERY blocks — amortize the key stream 4x.
// 256 blocks x 512 thr (8 waves). Block = (batch, 64 queries = 4 tiles);
// wave w covers keys [w*512, +512) and serves ALL 4 q-tiles from one set of
// f/vT loads (L1 traffic 590 MB -> 147 MB total; this was the ~40 us
// plateau). Inner machinery per tile is R11's verified shuffle-free path:
// key-permuted scores -> exp results ARE PV B-frags; V^T A-frags contiguous;
// ones-A MFMA denominator. Combine: 4 sequential LDS phases (one per tile).
// __launch_bounds__(512,2): VGPR cap 256 — no squeeze (R10 lesson).
// ---------------------------------------------------------------------------
__device__ __forceinline__ unsigned pack_bf16_2(float lo, float hi) {
  float2 f2; f2.x = lo; f2.y = hi;
  __hip_bfloat162 h2 = __float22bfloat162_rn(f2);
  return *reinterpret_cast<unsigned*>(&h2);
}

__global__ __launch_bounds__(512, 2) void attn_kernel(
    const _Float16* __restrict__ fh,        // [B][N][8] f16, key-permuted slots
    const _Float16* __restrict__ gh,        // [B][N][8] f16 (x log2e)
    const unsigned short* __restrict__ vT,  // [b][kblock][ch][r] bf16
    float* __restrict__ out)                // [B][N][64] f32
{
  const int N    = 4096;
  const int lane = threadIdx.x & 63;
  const int w    = threadIdx.x >> 6;       // 0..7 = key range
  const int quad = lane >> 4;
  const int l15  = lane & 15;

  __shared__ float red[7][64][17];  // per-phase: waves 1-7, 16 acc + 1 l

  const int xcd = blockIdx.x & 7;
  const int b   = xcd >> 1;
  const int qg  = ((blockIdx.x >> 3) << 1) + (xcd & 1);  // 0..63
  const int q0  = qg * 64;
  const int kbase = w * 512;

  const _Float16* fbase = fh + (size_t)b * N * 8;
  const _Float16* gbase = gh + (size_t)b * N * 8;
  const short*    vbat  = (const short*)vT + (size_t)b * 262144 + (l15 << 5) + (quad << 3);

  // G B-frags for the 4 q-tiles (quad 0 lanes carry k<8)
  half8_t gfrag[4] = {{}, {}, {}, {}};
  if (quad == 0) {
#pragma unroll
    for (int tt = 0; tt < 4; tt++)
      gfrag[tt] = *(const half8_t*)(gbase + (size_t)(q0 + tt * 16 + l15) * 8);
  }

  const f32x4 zc = {0.f, 0.f, 0.f, 0.f};
  f32x4 acc[4][4];   // [tile][ct]: out^T[ch=ct*16+quad*4+reg][q=l15]
  f32x4 acc4[4];     // [tile]: every reg = l[q=l15] partial
#pragma unroll
  for (int tt = 0; tt < 4; tt++) {
    acc4[tt] = zc;
#pragma unroll
    for (int ct = 0; ct < 4; ct++) acc[tt][ct] = zc;
  }

  short8_t ones8;
#pragma unroll
  for (int i = 0; i < 8; i++) ones8[i] = (short)0x3F80;  // bf16 1.0

  half8_t f0 = {}, f1 = {};          // zero-init once; non-quad0 lanes stay 0

#pragma unroll 2
  for (int cc = 0; cc < 16; cc++) {
    const int k0 = kbase + cc * 32;

    if (quad == 0) {
      f0 = *(const half8_t*)(fbase + (size_t)(k0 + l15) * 8);
      f1 = *(const half8_t*)(fbase + (size_t)(k0 + 16 + l15) * 8);
    }
    const short* vk = vbat + ((size_t)(k0 >> 5) << 11);
    short8_t v0 = *(const short8_t*)(vk);
    short8_t v1 = *(const short8_t*)(vk + 512);
    short8_t v2 = *(const short8_t*)(vk + 1024);
    short8_t v3 = *(const short8_t*)(vk + 1536);

#pragma unroll
    for (int tt = 0; tt < 4; tt++) {
      f32x4 s0 = __builtin_amdgcn_mfma_f32_16x16x32_f16(f0, gfrag[tt], zc, 0, 0, 0);
      f32x4 s1 = __builtin_amdgcn_mfma_f32_16x16x32_f16(f1, gfrag[tt], zc, 0, 0, 0);
      // key permutation => lane holds S^T for keys k0+quad*8+{0..3} (s0),
      //                                         k0+quad*8+{4..7} (s1), q=l15

      float p00 = __builtin_amdgcn_exp2f(s0[0]), p01 = __builtin_amdgcn_exp2f(s0[1]);
      float p02 = __builtin_amdgcn_exp2f(s0[2]), p03 = __builtin_amdgcn_exp2f(s0[3]);
      float p10 = __builtin_amdgcn_exp2f(s1[0]), p11 = __builtin_amdgcn_exp2f(s1[1]);
      float p12 = __builtin_amdgcn_exp2f(s1[2]), p13 = __builtin_amdgcn_exp2f(s1[3]);

      union { unsigned u[4]; short8_t v; } pu;
      pu.u[0] = pack_bf16_2(p00, p01);
      pu.u[1] = pack_bf16_2(p02, p03);
      pu.u[2] = pack_bf16_2(p10, p11);
      pu.u[3] = pack_bf16_2(p12, p13);
      short8_t pfrag = pu.v;  // direct PV B-operand, zero cross-lane ops

      acc[tt][0] = __builtin_amdgcn_mfma_f32_16x16x32_bf16(v0, pfrag, acc[tt][0], 0, 0, 0);
      acc[tt][1] = __builtin_amdgcn_mfma_f32_16x16x32_bf16(v1, pfrag, acc[tt][1], 0, 0, 0);
      acc[tt][2] = __builtin_amdgcn_mfma_f32_16x16x32_bf16(v2, pfrag, acc[tt][2], 0, 0, 0);
      acc[tt][3] = __builtin_amdgcn_mfma_f32_16x16x32_bf16(v3, pfrag, acc[tt][3], 0, 0, 0);
      acc4[tt]   = __builtin_amdgcn_mfma_f32_16x16x32_bf16(ones8, pfrag, acc4[tt], 0, 0, 0);
    }
  }

  // ---- cross-wave combine: 4 sequential phases, one q-tile each ----
#pragma unroll 1
  for (int tt = 0; tt < 4; tt++) {
    if (w > 0) {
      float* p = &red[w - 1][lane][0];
#pragma unroll
      for (int ct = 0; ct < 4; ct++)
#pragma unroll
        for (int reg = 0; reg < 4; reg++) p[ct * 4 + reg] = acc[tt][ct][reg];
      p[16] = acc4[tt][0];
    }
    __syncthreads();
    if (w == 0) {
      f32x4 a0 = acc[tt][0], a1 = acc[tt][1], a2 = acc[tt][2], a3 = acc[tt][3];
      float lv = acc4[tt][0];
#pragma unroll
      for (int ww = 0; ww < 7; ww++) {
        const float* p = &red[ww][lane][0];
#pragma unroll
        for (int reg = 0; reg < 4; reg++) {
          a0[reg] += p[0 + reg];
          a1[reg] += p[4 + reg];
          a2[reg] += p[8 + reg];
          a3[reg] += p[12 + reg];
        }
        lv += p[16];
      }
      const float inv = 1.0f / lv;   // this lane's q = l15
      float* ob = out + ((size_t)b * N + q0 + tt * 16 + l15) * 64 + (quad << 2);
      *(f32x4*)(ob)      = a0 * inv;
      *(f32x4*)(ob + 16) = a1 * inv;
      *(f32x4*)(ob + 32) = a2 * inv;
      *(f32x4*)(ob + 48) = a3 * inv;
    }
    __syncthreads();
  }
}

// ---------------------------------------------------------------------------
extern "C" void kernel_launch(void* const* d_in, const int* in_sizes, int n_in,
                              void* d_out, int out_size, void* d_ws, size_t ws_size,
                              hipStream_t stream) {
  const float* x  = (const float*)d_in[0];
  const float* Wf = (const float*)d_in[1];
  const float* bf = (const float*)d_in[2];
  const float* Wg = (const float*)d_in[3];
  const float* bg = (const float*)d_in[4];
  const float* Wh = (const float*)d_in[5];
  const float* bh = (const float*)d_in[6];
  float* out = (float*)d_out;

  char* ws = (char*)d_ws;
  _Float16* fh = (_Float16*)ws;                        // 256 KB
  _Float16* gh = (_Float16*)(ws + 262144);             // 256 KB
  unsigned short* vT = (unsigned short*)(ws + 524288); // 2 MB

  prep_kernel<<<512, 256, 0, stream>>>(x, Wf, bf, Wg, bg, Wh, bh, fh, gh, vT);
  attn_kernel<<<256, 512, 0, stream>>>(fh, gh, vT, out);
}

// Round 13
// 104.344 us; speedup vs baseline: 1.1584x; 1.0278x over previous
//
#include <hip/hip_runtime.h>
#include <hip/hip_bf16.h>
#include <hip/hip_fp16.h>

typedef _Float16 half8_t  __attribute__((ext_vector_type(8)));
typedef short    short8_t __attribute__((ext_vector_type(8)));
typedef short    short4_t __attribute__((ext_vector_type(4)));
typedef float    f32x4    __attribute__((ext_vector_type(4)));

#define LOG2E 1.44269504088896f

__device__ __forceinline__ unsigned pack_bf16_2(float lo, float hi) {
  float2 f2; f2.x = lo; f2.y = hi;
  __hip_bfloat162 h2 = __float22bfloat162_rn(f2);
  return *reinterpret_cast<unsigned*>(&h2);
}

// ---------------------------------------------------------------------------
// Kernel 1 (v8): MFMA prep. One block = 64 positions; wave w = 16-pos m-tile.
// C = x[64pos x 64c] @ W[64c x 80ch] via 16x16x32 f16 MFMA (fp32 acc), W^T
// staged in LDS ([ch][c], stride 72 halves -> 2-way-free b128 frag reads).
// Epilogue writes attn's exact layouts:
//   f  (ch 0-7):  key-permuted slots   (slot = (j<4)? q8*4+j : 16+q8*4+j-4)
//   g  (ch 8-15): [pos][8], W/b pre-scaled by log2e
//   vT4(ch16-79): [b][kblock][ch][r] bf16, one short4 store per lane/tile
// ---------------------------------------------------------------------------
__global__ __launch_bounds__(256) void prep_kernel(
    const float* __restrict__ x,
    const float* __restrict__ Wf, const float* __restrict__ bf,
    const float* __restrict__ Wg, const float* __restrict__ bg,
    const float* __restrict__ Wh, const float* __restrict__ bh,
    _Float16* __restrict__ fh, _Float16* __restrict__ gh,
    unsigned short* __restrict__ vT)
{
  __shared__ _Float16 WtT[80 * 72];   // [ch][c], stride 72
  __shared__ float ball[80];
  const int t = threadIdx.x;

  for (int i = t; i < 512; i += 256) {         // Wf/Wg: [c][d] -> WtT[d][c]
    int c = i >> 3, d = i & 7;
    WtT[d * 72 + c]       = (_Float16)Wf[i];
    WtT[(8 + d) * 72 + c] = (_Float16)(Wg[i] * LOG2E);
  }
  for (int i = t; i < 4096; i += 256) {        // Wh: [c][ch] -> WtT[16+ch][c]
    int c = i >> 6, ch = i & 63;
    WtT[(16 + ch) * 72 + c] = (_Float16)Wh[i];
  }
  if (t < 80) ball[t] = (t < 8) ? bf[t] : (t < 16) ? bg[t - 8] * LOG2E : bh[t - 16];
  __syncthreads();

  const int lane = t & 63, w = t >> 6;
  const int quad = lane >> 4, l15 = lane & 15;
  const int p0 = blockIdx.x * 64;              // flat position base
  const int row = p0 + w * 16 + l15;           // A-frag row (position)

  // A-frags: x[row][quad*8..+7] (k-chunk 0) and [32+quad*8..+7] (chunk 1)
  const float* xr = x + (size_t)row * 64 + quad * 8;
  float4 xa = *(const float4*)(xr);
  float4 xb = *(const float4*)(xr + 4);
  float4 xc = *(const float4*)(xr + 32);
  float4 xd = *(const float4*)(xr + 36);
  half8_t a0, a1;
  a0[0]=(_Float16)xa.x; a0[1]=(_Float16)xa.y; a0[2]=(_Float16)xa.z; a0[3]=(_Float16)xa.w;
  a0[4]=(_Float16)xb.x; a0[5]=(_Float16)xb.y; a0[6]=(_Float16)xb.z; a0[7]=(_Float16)xb.w;
  a1[0]=(_Float16)xc.x; a1[1]=(_Float16)xc.y; a1[2]=(_Float16)xc.z; a1[3]=(_Float16)xc.w;
  a1[4]=(_Float16)xd.x; a1[5]=(_Float16)xd.y; a1[6]=(_Float16)xd.z; a1[7]=(_Float16)xd.w;

  const f32x4 zc = {0.f, 0.f, 0.f, 0.f};
  const int b     = p0 >> 12;
  const int nbase = (p0 & 4095) + w * 16 + quad * 4;  // position of reg 0
  const int kblock = nbase >> 5;
  const int r0     = nbase & 31;
  // f slot permutation for this lane's 4 consecutive positions (same j-group)
  const int q8 = r0 >> 3, j8 = r0 & 7;
  const int slot0 = (j8 < 4) ? (q8 * 4 + j8) : (16 + q8 * 4 + (j8 - 4));
  const size_t fbase_out = ((size_t)b * 4096 + (kblock << 5) + slot0) * 8;
  const size_t gbase_out = ((size_t)p0 + w * 16 + quad * 4) * 8;
  const size_t vbase_out = (((size_t)b * 128 + kblock) << 11) + r0;

#pragma unroll
  for (int nt = 0; nt < 5; nt++) {
    const int ch0 = nt * 16 + l15;
    const _Float16* wt = &WtT[ch0 * 72 + quad * 8];
    half8_t b0 = *(const half8_t*)(wt);
    half8_t b1 = *(const half8_t*)(wt + 32);
    f32x4 d = __builtin_amdgcn_mfma_f32_16x16x32_f16(a0, b0, zc, 0, 0, 0);
    d = __builtin_amdgcn_mfma_f32_16x16x32_f16(a1, b1, d, 0, 0, 0);
    const float bias = ball[ch0];
    // d[reg] = out[pos = w*16+quad*4+reg][ch0]
    if (nt == 0) {
      if (l15 < 8) {
#pragma unroll
        for (int reg = 0; reg < 4; reg++)        // slots consecutive in reg
          fh[fbase_out + (size_t)reg * 8 + l15] = (_Float16)(d[reg] + bias);
      } else {
#pragma unroll
        for (int reg = 0; reg < 4; reg++)
          gh[gbase_out + (size_t)reg * 8 + (l15 - 8)] = (_Float16)(d[reg] + bias);
      }
    } else {
      const int vch = ch0 - 16;
      union { unsigned u[2]; short4_t s; } pk;
      pk.u[0] = pack_bf16_2(d[0] + bias, d[1] + bias);
      pk.u[1] = pack_bf16_2(d[2] + bias, d[3] + bias);
      *(short4_t*)(vT + vbase_out + (size_t)vch * 32) = pk.s;
    }
  }
}

// ---------------------------------------------------------------------------
// Kernel 2 (v13): R12's 64-query shuffle-free flash attention + explicit
// ping-pong register prefetch (next iteration's f/vT loads issued before the
// current 4-tile compute -> ~450 cyc of latency cover; R11's VGPR=44 showed
// the compiler pipelines nothing on its own). (512,2): no register squeeze.
// ---------------------------------------------------------------------------
__global__ __launch_bounds__(512, 2) void attn_kernel(
    const _Float16* __restrict__ fh,        // [B][N][8] f16, key-permuted slots
    const _Float16* __restrict__ gh,        // [B][N][8] f16 (x log2e)
    const unsigned short* __restrict__ vT,  // [b][kblock][ch][r] bf16
    float* __restrict__ out)                // [B][N][64] f32
{
  const int N    = 4096;
  const int lane = threadIdx.x & 63;
  const int w    = threadIdx.x >> 6;       // 0..7 = key range
  const int quad = lane >> 4;
  const int l15  = lane & 15;

  __shared__ float red[7][64][17];

  const int xcd = blockIdx.x & 7;
  const int b   = xcd >> 1;
  const int qg  = ((blockIdx.x >> 3) << 1) + (xcd & 1);  // 0..63
  const int q0  = qg * 64;
  const int kbase = w * 512;

  const _Float16* fbase = fh + (size_t)b * N * 8;
  const _Float16* gbase = gh + (size_t)b * N * 8;
  const short*    vbat  = (const short*)vT + (size_t)b * 262144 + (l15 << 5) + (quad << 3);

  half8_t gfrag[4] = {{}, {}, {}, {}};
  if (quad == 0) {
#pragma unroll
    for (int tt = 0; tt < 4; tt++)
      gfrag[tt] = *(const half8_t*)(gbase + (size_t)(q0 + tt * 16 + l15) * 8);
  }

  const f32x4 zc = {0.f, 0.f, 0.f, 0.f};
  f32x4 acc[4][4];
  f32x4 acc4[4];
#pragma unroll
  for (int tt = 0; tt < 4; tt++) {
    acc4[tt] = zc;
#pragma unroll
    for (int ct = 0; ct < 4; ct++) acc[tt][ct] = zc;
  }

  short8_t ones8;
#pragma unroll
  for (int i = 0; i < 8; i++) ones8[i] = (short)0x3F80;

  // ping-pong load buffers
  half8_t  fa0 = {}, fa1 = {}, fb0 = {}, fb1 = {};
  short8_t va0, va1, va2, va3, vb0, vb1, vb2, vb3;

  // prologue: load set A for cc = 0
  {
    const int k0 = kbase;
    if (quad == 0) {
      fa0 = *(const half8_t*)(fbase + (size_t)(k0 + l15) * 8);
      fa1 = *(const half8_t*)(fbase + (size_t)(k0 + 16 + l15) * 8);
    }
    const short* vk = vbat + ((size_t)(k0 >> 5) << 11);
    va0 = *(const short8_t*)(vk);
    va1 = *(const short8_t*)(vk + 512);
    va2 = *(const short8_t*)(vk + 1024);
    va3 = *(const short8_t*)(vk + 1536);
  }

  auto compute4 = [&](const half8_t& f0, const half8_t& f1,
                      const short8_t& v0, const short8_t& v1,
                      const short8_t& v2, const short8_t& v3) {
#pragma unroll
    for (int tt = 0; tt < 4; tt++) {
      f32x4 s0 = __builtin_amdgcn_mfma_f32_16x16x32_f16(f0, gfrag[tt], zc, 0, 0, 0);
      f32x4 s1 = __builtin_amdgcn_mfma_f32_16x16x32_f16(f1, gfrag[tt], zc, 0, 0, 0);
      float p00 = __builtin_amdgcn_exp2f(s0[0]), p01 = __builtin_amdgcn_exp2f(s0[1]);
      float p02 = __builtin_amdgcn_exp2f(s0[2]), p03 = __builtin_amdgcn_exp2f(s0[3]);
      float p10 = __builtin_amdgcn_exp2f(s1[0]), p11 = __builtin_amdgcn_exp2f(s1[1]);
      float p12 = __builtin_amdgcn_exp2f(s1[2]), p13 = __builtin_amdgcn_exp2f(s1[3]);
      union { unsigned u[4]; short8_t v; } pu;
      pu.u[0] = pack_bf16_2(p00, p01);
      pu.u[1] = pack_bf16_2(p02, p03);
      pu.u[2] = pack_bf16_2(p10, p11);
      pu.u[3] = pack_bf16_2(p12, p13);
      short8_t pfrag = pu.v;
      acc[tt][0] = __builtin_amdgcn_mfma_f32_16x16x32_bf16(v0, pfrag, acc[tt][0], 0, 0, 0);
      acc[tt][1] = __builtin_amdgcn_mfma_f32_16x16x32_bf16(v1, pfrag, acc[tt][1], 0, 0, 0);
      acc[tt][2] = __builtin_amdgcn_mfma_f32_16x16x32_bf16(v2, pfrag, acc[tt][2], 0, 0, 0);
      acc[tt][3] = __builtin_amdgcn_mfma_f32_16x16x32_bf16(v3, pfrag, acc[tt][3], 0, 0, 0);
      acc4[tt]   = __builtin_amdgcn_mfma_f32_16x16x32_bf16(ones8, pfrag, acc4[tt], 0, 0, 0);
    }
  };

#pragma unroll 1
  for (int cc = 0; cc < 16; cc += 2) {
    // issue loads for cc+1 into B, then compute A
    {
      const int k1 = kbase + (cc + 1) * 32;
      if (quad == 0) {
        fb0 = *(const half8_t*)(fbase + (size_t)(k1 + l15) * 8);
        fb1 = *(const half8_t*)(fbase + (size_t)(k1 + 16 + l15) * 8);
      }
      const short* vk = vbat + ((size_t)(k1 >> 5) << 11);
      vb0 = *(const short8_t*)(vk);
      vb1 = *(const short8_t*)(vk + 512);
      vb2 = *(const short8_t*)(vk + 1024);
      vb3 = *(const short8_t*)(vk + 1536);
    }
    compute4(fa0, fa1, va0, va1, va2, va3);
    // issue loads for cc+2 into A, then compute B
    if (cc + 2 < 16) {
      const int k2 = kbase + (cc + 2) * 32;
      if (quad == 0) {
        fa0 = *(const half8_t*)(fbase + (size_t)(k2 + l15) * 8);
        fa1 = *(const half8_t*)(fbase + (size_t)(k2 + 16 + l15) * 8);
      }
      const short* vk = vbat + ((size_t)(k2 >> 5) << 11);
      va0 = *(const short8_t*)(vk);
      va1 = *(const short8_t*)(vk + 512);
      va2 = *(const short8_t*)(vk + 1024);
      va3 = *(const short8_t*)(vk + 1536);
    }
    compute4(fb0, fb1, vb0, vb1, vb2, vb3);
  }

  // ---- cross-wave combine: 4 sequential phases ----
#pragma unroll 1
  for (int tt = 0; tt < 4; tt++) {
    if (w > 0) {
      float* p = &red[w - 1][lane][0];
#pragma unroll
      for (int ct = 0; ct < 4; ct++)
#pragma unroll
        for (int reg = 0; reg < 4; reg++) p[ct * 4 + reg] = acc[tt][ct][reg];
      p[16] = acc4[tt][0];
    }
    __syncthreads();
    if (w == 0) {
      f32x4 a0 = acc[tt][0], a1 = acc[tt][1], a2 = acc[tt][2], a3 = acc[tt][3];
      float lv = acc4[tt][0];
#pragma unroll
      for (int ww = 0; ww < 7; ww++) {
        const float* p = &red[ww][lane][0];
#pragma unroll
        for (int reg = 0; reg < 4; reg++) {
          a0[reg] += p[0 + reg];
          a1[reg] += p[4 + reg];
          a2[reg] += p[8 + reg];
          a3[reg] += p[12 + reg];
        }
        lv += p[16];
      }
      const float inv = 1.0f / lv;
      float* ob = out + ((size_t)b * N + q0 + tt * 16 + l15) * 64 + (quad << 2);
      *(f32x4*)(ob)      = a0 * inv;
      *(f32x4*)(ob + 16) = a1 * inv;
      *(f32x4*)(ob + 32) = a2 * inv;
      *(f32x4*)(ob + 48) = a3 * inv;
    }
    __syncthreads();
  }
}

// ---------------------------------------------------------------------------
extern "C" void kernel_launch(void* const* d_in, const int* in_sizes, int n_in,
                              void* d_out, int out_size, void* d_ws, size_t ws_size,
                              hipStream_t stream) {
  const float* x  = (const float*)d_in[0];
  const float* Wf = (const float*)d_in[1];
  const float* bf = (const float*)d_in[2];
  const float* Wg = (const float*)d_in[3];
  const float* bg = (const float*)d_in[4];
  const float* Wh = (const float*)d_in[5];
  const float* bh = (const float*)d_in[6];
  float* out = (float*)d_out;

  char* ws = (char*)d_ws;
  _Float16* fh = (_Float16*)ws;                        // 256 KB
  _Float16* gh = (_Float16*)(ws + 262144);             // 256 KB
  unsigned short* vT = (unsigned short*)(ws + 524288); // 2 MB

  prep_kernel<<<256, 256, 0, stream>>>(x, Wf, bf, Wg, bg, Wh, bh, fh, gh, vT);
  attn_kernel<<<256, 512, 0, stream>>>(fh, gh, vT, out);
}